// Round 13
// baseline (278.105 us; speedup 1.0000x reference)
//
#include <hip/hip_runtime.h>
#include <hip/hip_bf16.h>

typedef short bf16x8 __attribute__((ext_vector_type(8)));
typedef float f32x4 __attribute__((ext_vector_type(4)));
typedef _Float16 f16x2 __attribute__((ext_vector_type(2)));
typedef unsigned int u32;

static __device__ __forceinline__ unsigned short f2bf_rne(float f) {
    unsigned int u = __float_as_uint(f);
    u += 0x7fff + ((u >> 16) & 1);
    return (unsigned short)(u >> 16);
}
static __device__ __forceinline__ float bf2f(unsigned short h) {
    return __uint_as_float(((unsigned int)h) << 16);
}
// pack fp32 -> (bf16 hi << 16) | bf16 lo   (hi+lo reconstruct f to ~2^-16 rel)
static __device__ __forceinline__ u32 packsplit(float f) {
    unsigned short h = f2bf_rne(f);
    unsigned short l = f2bf_rne(f - bf2f(h));
    return ((u32)h << 16) | l;
}

// split one fp32 weight element into hi/lo bf16 at its fragment-ordered slot
// B-frag layout for mfma_f32_16x16x32_bf16: lane=quad*16+(n&15) holds k=kc*32+quad*8+j
static __device__ __forceinline__ void wsplit_one(const float* W, unsigned short* hi,
                                                  unsigned short* lo, int BN, int idx) {
    int k = idx / BN, n = idx % BN;
    float w = W[idx];
    unsigned short h = f2bf_rne(w);
    unsigned short l = f2bf_rne(w - bf2f(h));
    int CT = BN >> 4;
    int kc = k >> 5, quad = (k >> 3) & 3, j = k & 7;
    int ct = n >> 4, c = n & 15;
    int slot = (((kc * CT + ct) * 4 + quad) * 16 + c) * 8 + j;
    hi[slot] = h;
    lo[slot] = l;
}

// ===================== GEMM body — R13: NO LDS, no barriers =====================
// R12 analysis: inline fp32->bf16 hi/lo split (~100 VALU/thread/kc) + LDS round-trip
// dominated the 24 MFMAs. A is now PRE-SPLIT packed u32 (hi<<16|lo) by the producer;
// each lane loads its A-frag straight from global in frag order (rows = one wave's
// 16-row tile; 128B contiguous per row per kc — lines fully consumed), unpacks with
// shifts, streams MFMAs. BM=64 (R11 lesson: keep >=2-3 blocks/CU).

template<int BN>
static __device__ __forceinline__ void gemm_body(const u32* __restrict__ A,
                        const unsigned short* __restrict__ Whi, const unsigned short* __restrict__ Wlo,
                        _Float16* __restrict__ C, int N, int blk) {
    constexpr int CT = BN / 16;
    const int tid = threadIdx.x;
    const int wave = tid >> 6;
    const int lane = tid & 63;
    const int quad = lane >> 4;
    const int c16 = lane & 15;
    const int row0 = blk * 64;

    const int arow = row0 + wave * 16 + c16;          // A-frag m index = lane&15
    const bool valid = arow < N;
    const u32* ar = A + (size_t)arow * 128;

    // load whole row's fragments up-front: 8 x uint4 = 128B/lane (compiler hoists, deep MLP)
    uint4 a[8];
    #pragma unroll
    for (int i = 0; i < 8; ++i) {
        int off = (i >> 1) * 32 + quad * 8 + (i & 1) * 4;   // kc=i>>1, half=i&1
        a[i] = valid ? *(const uint4*)&ar[off] : make_uint4(0, 0, 0, 0);
    }

    f32x4 acc[CT];
    #pragma unroll
    for (int t = 0; t < CT; ++t) acc[t] = (f32x4){0.f, 0.f, 0.f, 0.f};

    #pragma unroll
    for (int kc = 0; kc < 4; ++kc) {
        uint4 a0 = a[kc * 2], a1 = a[kc * 2 + 1];
        union { u32 u[4]; bf16x8 v; } hi, lo;
        hi.u[0] = (a0.x >> 16) | (a0.y & 0xffff0000u);
        hi.u[1] = (a0.z >> 16) | (a0.w & 0xffff0000u);
        hi.u[2] = (a1.x >> 16) | (a1.y & 0xffff0000u);
        hi.u[3] = (a1.z >> 16) | (a1.w & 0xffff0000u);
        lo.u[0] = (a0.x & 0xffffu) | (a0.y << 16);
        lo.u[1] = (a0.z & 0xffffu) | (a0.w << 16);
        lo.u[2] = (a1.x & 0xffffu) | (a1.y << 16);
        lo.u[3] = (a1.z & 0xffffu) | (a1.w << 16);

        #pragma unroll
        for (int ct = 0; ct < CT; ++ct) {
            size_t bslot = ((size_t)(kc * CT + ct) * 64 + lane) * 8;
            bf16x8 bhi = *(const bf16x8*)&Whi[bslot];
            bf16x8 blo = *(const bf16x8*)&Wlo[bslot];
            acc[ct] = __builtin_amdgcn_mfma_f32_16x16x32_bf16(hi.v, bhi, acc[ct], 0, 0, 0);
            acc[ct] = __builtin_amdgcn_mfma_f32_16x16x32_bf16(hi.v, blo, acc[ct], 0, 0, 0);
            acc[ct] = __builtin_amdgcn_mfma_f32_16x16x32_bf16(lo.v, bhi, acc[ct], 0, 0, 0);
        }
    }

    // C/D layout: col = lane&15, row = quad*4 + reg
    #pragma unroll
    for (int ct = 0; ct < CT; ++ct) {
        #pragma unroll
        for (int r = 0; r < 4; ++r) {
            int grow = row0 + wave * 16 + quad * 4 + r;
            if (grow < N) C[(size_t)grow * BN + ct * 16 + c16] = (_Float16)acc[ct][r];
        }
    }
}

// ===================== preprocessing =====================

// phase 0: in-degree count + rank capture + weight split + x pre-split (packed u32).
// Atomic-latency-bound => the streamed x-split (51MB) rides along nearly free.
__global__ __launch_bounds__(256) void k_count_wsplit(const int* __restrict__ dst, int* __restrict__ deg,
                          int* __restrict__ rank,
                          const float* __restrict__ x, u32* __restrict__ xsplit,
                          const float* __restrict__ W1, const float* __restrict__ W2, const float* __restrict__ W3,
                          unsigned short* __restrict__ W1hi, unsigned short* __restrict__ W1lo,
                          unsigned short* __restrict__ W2hi, unsigned short* __restrict__ W2lo,
                          unsigned short* __restrict__ W3hi, unsigned short* __restrict__ W3lo,
                          int E, int nElem) {
    int e = blockIdx.x * blockDim.x + threadIdx.x;
    int gsz = gridDim.x * blockDim.x;
    if (e < E) rank[e] = atomicAdd(&deg[dst[e]], 1);
    if (e < 128 * 128) {
        wsplit_one(W1, W1hi, W1lo, 128, e);
        wsplit_one(W2, W2hi, W2lo, 128, e);
    }
    if (e < 128 * 64) wsplit_one(W3, W3hi, W3lo, 64, e);
    // x -> packed split, float4-wise grid-stride
    int nF4 = nElem >> 2;
    for (int i = e; i < nF4; i += gsz) {
        float4 v = ((const float4*)x)[i];
        uint4 p;
        p.x = packsplit(v.x);
        p.y = packsplit(v.y);
        p.z = packsplit(v.z);
        p.w = packsplit(v.w);
        ((uint4*)xsplit)[i] = p;
    }
}

// single-kernel scan: each of 49 blocks reduces preceding degrees for its prefix, then
// scans its 1024-chunk; emits dinv.
__global__ __launch_bounds__(1024) void k_scan(const int* __restrict__ deg, float* __restrict__ dinv,
                                               int* __restrict__ row_start, int N) {
    __shared__ int s[1024];
    __shared__ int wsum[16];
    __shared__ int prefix;
    const int t = threadIdx.x;
    const int base = blockIdx.x * 1024;

    {
        int v = 0;
        for (int j = t; j < base; j += 1024) v += deg[j];
        for (int off = 32; off > 0; off >>= 1) v += __shfl_down(v, off, 64);
        if ((t & 63) == 0) wsum[t >> 6] = v;
        __syncthreads();
        if (t == 0) {
            int acc = 0;
            #pragma unroll
            for (int k = 0; k < 16; ++k) acc += wsum[k];
            prefix = acc;
        }
    }

    int i = base + t;
    int v = 0;
    if (i < N) {
        v = deg[i];
        dinv[i] = rsqrtf((float)v + 1.0f);
    }
    s[t] = v;
    __syncthreads();
    for (int off = 1; off < 1024; off <<= 1) {
        int x = (t >= off) ? s[t - off] : 0;
        __syncthreads();
        s[t] += x;
        __syncthreads();
    }
    if (i <= N) row_start[i] = prefix + s[t] - v;   // row_start[N] = E via deg-past-N = 0
}

// ===================== fused: layer-1 GEMM + CSR scatter (independent work) =====================

__global__ __launch_bounds__(256, 3) void k_gemm1_scatter(const u32* __restrict__ A,
                          const unsigned short* __restrict__ Whi, const unsigned short* __restrict__ Wlo,
                          _Float16* __restrict__ C, int N, int gemmGrid,
                          const int* __restrict__ src, const int* __restrict__ dst,
                          const int* __restrict__ row_start, const int* __restrict__ rank,
                          const float* __restrict__ dinv, int2* __restrict__ cv, int E) {
    if ((int)blockIdx.x < gemmGrid) {
        gemm_body<128>(A, Whi, Wlo, C, N, blockIdx.x);
    } else {
        int e = (blockIdx.x - gemmGrid) * 256 + threadIdx.x;
        if (e < E) {
            int d = dst[e];
            int s = src[e];
            cv[row_start[d] + rank[e]] = make_int2(s, __float_as_int(dinv[s]));
        }
    }
}

// plain GEMM kernels for layers 2/3
template<int BN>
__global__ __launch_bounds__(256, 3) void k_gemm_mfma(const u32* __restrict__ A,
                        const unsigned short* __restrict__ Whi, const unsigned short* __restrict__ Wlo,
                        _Float16* __restrict__ C, int N) {
    gemm_body<BN>(A, Whi, Wlo, C, N, blockIdx.x);
}

// ===================== aggregation =====================
// One wave per node; header broadcast via readlane (SGPR, no DS ops); masked full-depth
// rounds of 16 gathers. t is fp16 (halves random-gather bytes).
// Output written as packed hi/lo u32 (GEMM A-operand) — split cost lives here, where
// the kernel is gather-latency-bound with spare VALU (R12 analysis).

__global__ __launch_bounds__(256) void k_agg128(const _Float16* __restrict__ t, u32* __restrict__ outp,
                      const int* __restrict__ row_start, const int2* __restrict__ cv,
                      const float* __restrict__ dinv, const float* __restrict__ bias,
                      int N) {
    int gid = blockIdx.x * blockDim.x + threadIdx.x;
    int node = gid >> 6;
    int lane = gid & 63;
    if (node >= N) return;
    int p = row_start[node];
    int end = row_start[node + 1];
    const f16x2* tp = (const f16x2*)t;
    float2 acc[4];
    #pragma unroll
    for (int j = 0; j < 4; ++j) acc[j] = make_float2(0.f, 0.f);

    while (p < end) {
        int idx = p + lane;
        int2 h = (idx < end) ? cv[idx] : make_int2(0, 0);   // invalid lanes: s=0, w=0
        int cnt = min(end - p, 64);
        int rounds = (cnt + 15) >> 4;
        for (int r = 0; r < rounds; ++r) {
            int base = r * 16;
            int s[16]; float w[16];
            #pragma unroll
            for (int j = 0; j < 16; ++j) {
                s[j] = __builtin_amdgcn_readlane(h.x, base + j);
                w[j] = __int_as_float(__builtin_amdgcn_readlane(h.y, base + j));
            }
            f16x2 v[16];
            #pragma unroll
            for (int j = 0; j < 16; ++j) v[j] = tp[s[j] * 64 + lane];
            #pragma unroll
            for (int j = 0; j < 16; ++j) {
                acc[j & 3].x += w[j] * (float)v[j].x;   // v_fma_mix_f32
                acc[j & 3].y += w[j] * (float)v[j].y;
            }
        }
        p += 64;
    }
    float di = dinv[node];
    f16x2 sv = tp[node * 64 + lane];
    float2 bv = ((const float2*)bias)[lane];
    float sx = (acc[0].x + acc[1].x) + (acc[2].x + acc[3].x);
    float sy = (acc[0].y + acc[1].y) + (acc[2].y + acc[3].y);
    float rx = fmaxf(di * sx + di * di * (float)sv.x + bv.x, 0.f);
    float ry = fmaxf(di * sy + di * di * (float)sv.y + bv.y, 0.f);
    ((uint2*)outp)[node * 64 + lane] = make_uint2(packsplit(rx), packsplit(ry));
}

// layer-3 aggregation (D=64, fp16 t) fused with final linear: out[i] = relu(agg_i + b) . Wf + bf
__global__ __launch_bounds__(256) void k_agg64_final(const _Float16* __restrict__ t, float* __restrict__ outp,
                      const int* __restrict__ row_start, const int2* __restrict__ cv,
                      const float* __restrict__ dinv, const float* __restrict__ bias,
                      const float* __restrict__ Wf, const float* __restrict__ bf,
                      int N) {
    int gid = blockIdx.x * blockDim.x + threadIdx.x;
    int node = gid >> 6;
    int lane = gid & 63;
    if (node >= N) return;
    int p = row_start[node];
    int end = row_start[node + 1];
    float acc[4] = {0.f, 0.f, 0.f, 0.f};

    while (p < end) {
        int idx = p + lane;
        int2 h = (idx < end) ? cv[idx] : make_int2(0, 0);
        int cnt = min(end - p, 64);
        int rounds = (cnt + 15) >> 4;
        for (int r = 0; r < rounds; ++r) {
            int base = r * 16;
            int s[16]; float w[16];
            #pragma unroll
            for (int j = 0; j < 16; ++j) {
                s[j] = __builtin_amdgcn_readlane(h.x, base + j);
                w[j] = __int_as_float(__builtin_amdgcn_readlane(h.y, base + j));
            }
            _Float16 v[16];
            #pragma unroll
            for (int j = 0; j < 16; ++j) v[j] = t[s[j] * 64 + lane];
            #pragma unroll
            for (int j = 0; j < 16; ++j) acc[j & 3] += w[j] * (float)v[j];
        }
        p += 64;
    }
    float di = dinv[node];
    float r = di * ((acc[0] + acc[1]) + (acc[2] + acc[3])) + di * di * (float)t[node * 64 + lane] + bias[lane];
    r = fmaxf(r, 0.f);
    float v = r * Wf[lane];
    for (int off = 32; off > 0; off >>= 1) v += __shfl_down(v, off, 64);
    if (lane == 0) outp[node] = v + bf[0];
}

// ===================== launch =====================

extern "C" void kernel_launch(void* const* d_in, const int* in_sizes, int n_in,
                              void* d_out, int out_size, void* d_ws, size_t ws_size,
                              hipStream_t stream) {
    const float* x  = (const float*)d_in[0];
    const int*   src = (const int*)d_in[1];
    const int*   dst = (const int*)d_in[2];
    const float* W1 = (const float*)d_in[3];
    const float* b1 = (const float*)d_in[4];
    const float* W2 = (const float*)d_in[5];
    const float* b2 = (const float*)d_in[6];
    const float* W3 = (const float*)d_in[7];
    const float* b3 = (const float*)d_in[8];
    const float* Wf = (const float*)d_in[9];
    const float* bf = (const float*)d_in[10];
    float* out = (float*)d_out;

    const int N = 50000;
    const int E = 800000;

    char* ws = (char*)d_ws;
    size_t off = 0;
    auto alloc = [&](size_t bytes) -> void* {
        void* p = (void*)(ws + off);
        off += (bytes + 511) & ~((size_t)511);
        return p;
    };
    int*   deg       = (int*)alloc((size_t)N * 4);
    float* dinv      = (float*)alloc((size_t)N * 4);
    int*   row_start = (int*)alloc((size_t)(N + 1) * 4);
    int*   rank      = (int*)alloc((size_t)E * 4);
    int2*  cv        = (int2*)alloc((size_t)E * 8);
    u32*   xsplit    = (u32*)alloc((size_t)N * 128 * 4);        // packed hi/lo of x
    _Float16* bufT   = (_Float16*)alloc((size_t)N * 128 * 2);   // GEMM out (gather source), fp16
    u32*   bufH      = (u32*)alloc((size_t)N * 128 * 4);        // agg out, packed hi/lo
    unsigned short* W1hi = (unsigned short*)alloc(128 * 128 * 2);
    unsigned short* W1lo = (unsigned short*)alloc(128 * 128 * 2);
    unsigned short* W2hi = (unsigned short*)alloc(128 * 128 * 2);
    unsigned short* W2lo = (unsigned short*)alloc(128 * 128 * 2);
    unsigned short* W3hi = (unsigned short*)alloc(128 * 64 * 2);
    unsigned short* W3lo = (unsigned short*)alloc(128 * 64 * 2);

    hipMemsetAsync(deg, 0, (size_t)N * 4, stream);

    k_count_wsplit<<<(E + 255) / 256, 256, 0, stream>>>(dst, deg, rank, x, xsplit, W1, W2, W3,
                                                        W1hi, W1lo, W2hi, W2lo, W3hi, W3lo,
                                                        E, N * 128);
    int NB = (N + 1023) / 1024;   // 49 blocks
    k_scan<<<NB, 1024, 0, stream>>>(deg, dinv, row_start, N);

    int gemmGrid = (N + 63) / 64;          // 782
    int scatGrid = (E + 255) / 256;        // 3125
    int aggGrid = (N * 64 + 255) / 256;

    // fused: layer-1 GEMM + scatter (independent work overlapped)
    k_gemm1_scatter<<<gemmGrid + scatGrid, 256, 0, stream>>>(xsplit, W1hi, W1lo, bufT, N, gemmGrid,
                                                             src, dst, row_start, rank, dinv, cv, E);
    k_agg128<<<aggGrid, 256, 0, stream>>>(bufT, bufH, row_start, cv, dinv, b1, N);
    // layer 2
    k_gemm_mfma<128><<<gemmGrid, 256, 0, stream>>>(bufH, W2hi, W2lo, bufT, N);
    k_agg128<<<aggGrid, 256, 0, stream>>>(bufT, bufH, row_start, cv, dinv, b2, N);
    // layer 3 (transform to 64 dims first, then aggregate + fused final linear)
    k_gemm_mfma<64><<<gemmGrid, 256, 0, stream>>>(bufH, W3hi, W3lo, bufT, N);
    k_agg64_final<<<aggGrid, 256, 0, stream>>>(bufT, out, row_start, cv, dinv, b3, Wf, bf, N);
}

// Round 14
// 277.021 us; speedup vs baseline: 1.0039x; 1.0039x over previous
//
#include <hip/hip_runtime.h>
#include <hip/hip_bf16.h>

typedef short bf16x8 __attribute__((ext_vector_type(8)));
typedef float f32x4 __attribute__((ext_vector_type(4)));
typedef _Float16 f16x2 __attribute__((ext_vector_type(2)));
typedef unsigned int u32;

static __device__ __forceinline__ unsigned short f2bf_rne(float f) {
    unsigned int u = __float_as_uint(f);
    u += 0x7fff + ((u >> 16) & 1);
    return (unsigned short)(u >> 16);
}
static __device__ __forceinline__ float bf2f(unsigned short h) {
    return __uint_as_float(((unsigned int)h) << 16);
}
// pack fp32 -> (bf16 hi << 16) | bf16 lo   (hi+lo reconstruct f to ~2^-16 rel)
static __device__ __forceinline__ u32 packsplit(float f) {
    unsigned short h = f2bf_rne(f);
    unsigned short l = f2bf_rne(f - bf2f(h));
    return ((u32)h << 16) | l;
}

// split one fp32 weight element into hi/lo bf16 at its fragment-ordered slot
// B-frag layout for mfma_f32_16x16x32_bf16: lane=quad*16+(n&15) holds k=kc*32+quad*8+j
static __device__ __forceinline__ void wsplit_one(const float* W, unsigned short* hi,
                                                  unsigned short* lo, int BN, int idx) {
    int k = idx / BN, n = idx % BN;
    float w = W[idx];
    unsigned short h = f2bf_rne(w);
    unsigned short l = f2bf_rne(w - bf2f(h));
    int CT = BN >> 4;
    int kc = k >> 5, quad = (k >> 3) & 3, j = k & 7;
    int ct = n >> 4, c = n & 15;
    int slot = (((kc * CT + ct) * 4 + quad) * 16 + c) * 8 + j;
    hi[slot] = h;
    lo[slot] = l;
}

// ===================== GEMM body — no LDS, no barriers (R13) =====================
// A is pre-split packed u32 (hi<<16|lo) by producers; lanes load A-frags straight from
// global in frag order, unpack with shifts, stream MFMAs. BM=64 (R11: >=2-3 blocks/CU).

template<int BN>
static __device__ __forceinline__ void gemm_body(const u32* __restrict__ A,
                        const unsigned short* __restrict__ Whi, const unsigned short* __restrict__ Wlo,
                        _Float16* __restrict__ C, int N, int blk) {
    constexpr int CT = BN / 16;
    const int tid = threadIdx.x;
    const int wave = tid >> 6;
    const int lane = tid & 63;
    const int quad = lane >> 4;
    const int c16 = lane & 15;
    const int row0 = blk * 64;

    const int arow = row0 + wave * 16 + c16;          // A-frag m index = lane&15
    const bool valid = arow < N;
    const u32* ar = A + (size_t)arow * 128;

    uint4 a[8];
    #pragma unroll
    for (int i = 0; i < 8; ++i) {
        int off = (i >> 1) * 32 + quad * 8 + (i & 1) * 4;   // kc=i>>1, half=i&1
        a[i] = valid ? *(const uint4*)&ar[off] : make_uint4(0, 0, 0, 0);
    }

    f32x4 acc[CT];
    #pragma unroll
    for (int t = 0; t < CT; ++t) acc[t] = (f32x4){0.f, 0.f, 0.f, 0.f};

    #pragma unroll
    for (int kc = 0; kc < 4; ++kc) {
        uint4 a0 = a[kc * 2], a1 = a[kc * 2 + 1];
        union { u32 u[4]; bf16x8 v; } hi, lo;
        hi.u[0] = (a0.x >> 16) | (a0.y & 0xffff0000u);
        hi.u[1] = (a0.z >> 16) | (a0.w & 0xffff0000u);
        hi.u[2] = (a1.x >> 16) | (a1.y & 0xffff0000u);
        hi.u[3] = (a1.z >> 16) | (a1.w & 0xffff0000u);
        lo.u[0] = (a0.x & 0xffffu) | (a0.y << 16);
        lo.u[1] = (a0.z & 0xffffu) | (a0.w << 16);
        lo.u[2] = (a1.x & 0xffffu) | (a1.y << 16);
        lo.u[3] = (a1.z & 0xffffu) | (a1.w << 16);

        #pragma unroll
        for (int ct = 0; ct < CT; ++ct) {
            size_t bslot = ((size_t)(kc * CT + ct) * 64 + lane) * 8;
            bf16x8 bhi = *(const bf16x8*)&Whi[bslot];
            bf16x8 blo = *(const bf16x8*)&Wlo[bslot];
            acc[ct] = __builtin_amdgcn_mfma_f32_16x16x32_bf16(hi.v, bhi, acc[ct], 0, 0, 0);
            acc[ct] = __builtin_amdgcn_mfma_f32_16x16x32_bf16(hi.v, blo, acc[ct], 0, 0, 0);
            acc[ct] = __builtin_amdgcn_mfma_f32_16x16x32_bf16(lo.v, bhi, acc[ct], 0, 0, 0);
        }
    }

    #pragma unroll
    for (int ct = 0; ct < CT; ++ct) {
        #pragma unroll
        for (int r = 0; r < 4; ++r) {
            int grow = row0 + wave * 16 + quad * 4 + r;
            if (grow < N) C[(size_t)grow * BN + ct * 16 + c16] = (_Float16)acc[ct][r];
        }
    }
}

// ===================== preprocessing =====================

// phase 0: in-degree count + rank capture + weight split.
// R14: x-split REMOVED — R13 showed streaming work does NOT hide under atomic-bound
// waves (count 43.7us, WRITE 53.6MB). It lives in k_scan's spare blocks instead.
__global__ __launch_bounds__(256) void k_count_wsplit(const int* __restrict__ dst, int* __restrict__ deg,
                          int* __restrict__ rank,
                          const float* __restrict__ W1, const float* __restrict__ W2, const float* __restrict__ W3,
                          unsigned short* __restrict__ W1hi, unsigned short* __restrict__ W1lo,
                          unsigned short* __restrict__ W2hi, unsigned short* __restrict__ W2lo,
                          unsigned short* __restrict__ W3hi, unsigned short* __restrict__ W3lo,
                          int E) {
    int e = blockIdx.x * blockDim.x + threadIdx.x;
    if (e < E) rank[e] = atomicAdd(&deg[dst[e]], 1);
    if (e < 128 * 128) {
        wsplit_one(W1, W1hi, W1lo, 128, e);
        wsplit_one(W2, W2hi, W2lo, 128, e);
    }
    if (e < 128 * 64) wsplit_one(W3, W3hi, W3lo, 64, e);
}

// heterogeneous: blocks [0,NB) = scan (prefix over degrees + dinv + row_start);
// blocks [NB, NB+391) = x pre-split stream (independent; overlaps scan's barriers).
__global__ __launch_bounds__(1024) void k_scan_xsplit(const int* __restrict__ deg, float* __restrict__ dinv,
                                               int* __restrict__ row_start, int N, int NB,
                                               const float* __restrict__ x, u32* __restrict__ xsplit,
                                               int nF4) {
    const int t = threadIdx.x;
    if ((int)blockIdx.x >= NB) {
        int i = (blockIdx.x - NB) * 1024 + t;
        if (i < nF4) {
            float4 v = ((const float4*)x)[i];
            uint4 p;
            p.x = packsplit(v.x);
            p.y = packsplit(v.y);
            p.z = packsplit(v.z);
            p.w = packsplit(v.w);
            ((uint4*)xsplit)[i] = p;
        }
        return;
    }
    __shared__ int s[1024];
    __shared__ int wsum[16];
    __shared__ int prefix;
    const int base = blockIdx.x * 1024;

    {
        int v = 0;
        for (int j = t; j < base; j += 1024) v += deg[j];
        for (int off = 32; off > 0; off >>= 1) v += __shfl_down(v, off, 64);
        if ((t & 63) == 0) wsum[t >> 6] = v;
        __syncthreads();
        if (t == 0) {
            int acc = 0;
            #pragma unroll
            for (int k = 0; k < 16; ++k) acc += wsum[k];
            prefix = acc;
        }
    }

    int i = base + t;
    int v = 0;
    if (i < N) {
        v = deg[i];
        dinv[i] = rsqrtf((float)v + 1.0f);
    }
    s[t] = v;
    __syncthreads();
    for (int off = 1; off < 1024; off <<= 1) {
        int x2 = (t >= off) ? s[t - off] : 0;
        __syncthreads();
        s[t] += x2;
        __syncthreads();
    }
    if (i <= N) row_start[i] = prefix + s[t] - v;   // row_start[N] = E via deg-past-N = 0
}

// ===================== fused: layer-1 GEMM + CSR scatter (independent work) =====================

__global__ __launch_bounds__(256, 3) void k_gemm1_scatter(const u32* __restrict__ A,
                          const unsigned short* __restrict__ Whi, const unsigned short* __restrict__ Wlo,
                          _Float16* __restrict__ C, int N, int gemmGrid,
                          const int* __restrict__ src, const int* __restrict__ dst,
                          const int* __restrict__ row_start, const int* __restrict__ rank,
                          const float* __restrict__ dinv, int2* __restrict__ cv, int E) {
    if ((int)blockIdx.x < gemmGrid) {
        gemm_body<128>(A, Whi, Wlo, C, N, blockIdx.x);
    } else {
        int e = (blockIdx.x - gemmGrid) * 256 + threadIdx.x;
        if (e < E) {
            int d = dst[e];
            int s = src[e];
            cv[row_start[d] + rank[e]] = make_int2(s, __float_as_int(dinv[s]));
        }
    }
}

// plain GEMM kernels for layers 2/3
template<int BN>
__global__ __launch_bounds__(256, 3) void k_gemm_mfma(const u32* __restrict__ A,
                        const unsigned short* __restrict__ Whi, const unsigned short* __restrict__ Wlo,
                        _Float16* __restrict__ C, int N) {
    gemm_body<BN>(A, Whi, Wlo, C, N, blockIdx.x);
}

// ===================== aggregation =====================
// One wave per node; readlane header broadcast (SGPR, no DS ops); masked rounds of 16
// gathers; fp16 gather source. Pinned at random-gather ceiling (R4-R6). Output written
// as packed hi/lo u32 (GEMM A-operand) — split hides under gather latency (R12 win).

__global__ __launch_bounds__(256) void k_agg128(const _Float16* __restrict__ t, u32* __restrict__ outp,
                      const int* __restrict__ row_start, const int2* __restrict__ cv,
                      const float* __restrict__ dinv, const float* __restrict__ bias,
                      int N) {
    int gid = blockIdx.x * blockDim.x + threadIdx.x;
    int node = gid >> 6;
    int lane = gid & 63;
    if (node >= N) return;
    int p = row_start[node];
    int end = row_start[node + 1];
    const f16x2* tp = (const f16x2*)t;
    float2 acc[4];
    #pragma unroll
    for (int j = 0; j < 4; ++j) acc[j] = make_float2(0.f, 0.f);

    while (p < end) {
        int idx = p + lane;
        int2 h = (idx < end) ? cv[idx] : make_int2(0, 0);   // invalid lanes: s=0, w=0
        int cnt = min(end - p, 64);
        int rounds = (cnt + 15) >> 4;
        for (int r = 0; r < rounds; ++r) {
            int base = r * 16;
            int s[16]; float w[16];
            #pragma unroll
            for (int j = 0; j < 16; ++j) {
                s[j] = __builtin_amdgcn_readlane(h.x, base + j);
                w[j] = __int_as_float(__builtin_amdgcn_readlane(h.y, base + j));
            }
            f16x2 v[16];
            #pragma unroll
            for (int j = 0; j < 16; ++j) v[j] = tp[s[j] * 64 + lane];
            #pragma unroll
            for (int j = 0; j < 16; ++j) {
                acc[j & 3].x += w[j] * (float)v[j].x;   // v_fma_mix_f32
                acc[j & 3].y += w[j] * (float)v[j].y;
            }
        }
        p += 64;
    }
    float di = dinv[node];
    f16x2 sv = tp[node * 64 + lane];
    float2 bv = ((const float2*)bias)[lane];
    float sx = (acc[0].x + acc[1].x) + (acc[2].x + acc[3].x);
    float sy = (acc[0].y + acc[1].y) + (acc[2].y + acc[3].y);
    float rx = fmaxf(di * sx + di * di * (float)sv.x + bv.x, 0.f);
    float ry = fmaxf(di * sy + di * di * (float)sv.y + bv.y, 0.f);
    ((uint2*)outp)[node * 64 + lane] = make_uint2(packsplit(rx), packsplit(ry));
}

// layer-3 aggregation (D=64, fp16 t) fused with final linear: out[i] = relu(agg_i + b) . Wf + bf
__global__ __launch_bounds__(256) void k_agg64_final(const _Float16* __restrict__ t, float* __restrict__ outp,
                      const int* __restrict__ row_start, const int2* __restrict__ cv,
                      const float* __restrict__ dinv, const float* __restrict__ bias,
                      const float* __restrict__ Wf, const float* __restrict__ bf,
                      int N) {
    int gid = blockIdx.x * blockDim.x + threadIdx.x;
    int node = gid >> 6;
    int lane = gid & 63;
    if (node >= N) return;
    int p = row_start[node];
    int end = row_start[node + 1];
    float acc[4] = {0.f, 0.f, 0.f, 0.f};

    while (p < end) {
        int idx = p + lane;
        int2 h = (idx < end) ? cv[idx] : make_int2(0, 0);
        int cnt = min(end - p, 64);
        int rounds = (cnt + 15) >> 4;
        for (int r = 0; r < rounds; ++r) {
            int base = r * 16;
            int s[16]; float w[16];
            #pragma unroll
            for (int j = 0; j < 16; ++j) {
                s[j] = __builtin_amdgcn_readlane(h.x, base + j);
                w[j] = __int_as_float(__builtin_amdgcn_readlane(h.y, base + j));
            }
            _Float16 v[16];
            #pragma unroll
            for (int j = 0; j < 16; ++j) v[j] = t[s[j] * 64 + lane];
            #pragma unroll
            for (int j = 0; j < 16; ++j) acc[j & 3] += w[j] * (float)v[j];
        }
        p += 64;
    }
    float di = dinv[node];
    float r = di * ((acc[0] + acc[1]) + (acc[2] + acc[3])) + di * di * (float)t[node * 64 + lane] + bias[lane];
    r = fmaxf(r, 0.f);
    float v = r * Wf[lane];
    for (int off = 32; off > 0; off >>= 1) v += __shfl_down(v, off, 64);
    if (lane == 0) outp[node] = v + bf[0];
}

// ===================== launch =====================

extern "C" void kernel_launch(void* const* d_in, const int* in_sizes, int n_in,
                              void* d_out, int out_size, void* d_ws, size_t ws_size,
                              hipStream_t stream) {
    const float* x  = (const float*)d_in[0];
    const int*   src = (const int*)d_in[1];
    const int*   dst = (const int*)d_in[2];
    const float* W1 = (const float*)d_in[3];
    const float* b1 = (const float*)d_in[4];
    const float* W2 = (const float*)d_in[5];
    const float* b2 = (const float*)d_in[6];
    const float* W3 = (const float*)d_in[7];
    const float* b3 = (const float*)d_in[8];
    const float* Wf = (const float*)d_in[9];
    const float* bf = (const float*)d_in[10];
    float* out = (float*)d_out;

    const int N = 50000;
    const int E = 800000;

    char* ws = (char*)d_ws;
    size_t off = 0;
    auto alloc = [&](size_t bytes) -> void* {
        void* p = (void*)(ws + off);
        off += (bytes + 511) & ~((size_t)511);
        return p;
    };
    int*   deg       = (int*)alloc((size_t)N * 4);
    float* dinv      = (float*)alloc((size_t)N * 4);
    int*   row_start = (int*)alloc((size_t)(N + 1) * 4);
    int*   rank      = (int*)alloc((size_t)E * 4);
    int2*  cv        = (int2*)alloc((size_t)E * 8);
    u32*   xsplit    = (u32*)alloc((size_t)N * 128 * 4);        // packed hi/lo of x
    _Float16* bufT   = (_Float16*)alloc((size_t)N * 128 * 2);   // GEMM out (gather source), fp16
    u32*   bufH      = (u32*)alloc((size_t)N * 128 * 4);        // agg out, packed hi/lo
    unsigned short* W1hi = (unsigned short*)alloc(128 * 128 * 2);
    unsigned short* W1lo = (unsigned short*)alloc(128 * 128 * 2);
    unsigned short* W2hi = (unsigned short*)alloc(128 * 128 * 2);
    unsigned short* W2lo = (unsigned short*)alloc(128 * 128 * 2);
    unsigned short* W3hi = (unsigned short*)alloc(128 * 64 * 2);
    unsigned short* W3lo = (unsigned short*)alloc(128 * 64 * 2);

    hipMemsetAsync(deg, 0, (size_t)N * 4, stream);

    k_count_wsplit<<<(E + 255) / 256, 256, 0, stream>>>(dst, deg, rank, W1, W2, W3,
                                                        W1hi, W1lo, W2hi, W2lo, W3hi, W3lo, E);
    int NB = (N + 1023) / 1024;            // 49 scan blocks
    int nF4 = (N * 128) / 4;               // 400000 uint4s of x
    int xBlocks = (nF4 + 1023) / 1024;     // 391
    k_scan_xsplit<<<NB + xBlocks, 1024, 0, stream>>>(deg, dinv, row_start, N, NB, x, xsplit, nF4);

    int gemmGrid = (N + 63) / 64;          // 782
    int scatGrid = (E + 255) / 256;        // 3125
    int aggGrid = (N * 64 + 255) / 256;

    // fused: layer-1 GEMM + scatter (independent work overlapped)
    k_gemm1_scatter<<<gemmGrid + scatGrid, 256, 0, stream>>>(xsplit, W1hi, W1lo, bufT, N, gemmGrid,
                                                             src, dst, row_start, rank, dinv, cv, E);
    k_agg128<<<aggGrid, 256, 0, stream>>>(bufT, bufH, row_start, cv, dinv, b1, N);
    // layer 2
    k_gemm_mfma<128><<<gemmGrid, 256, 0, stream>>>(bufH, W2hi, W2lo, bufT, N);
    k_agg128<<<aggGrid, 256, 0, stream>>>(bufT, bufH, row_start, cv, dinv, b2, N);
    // layer 3 (transform to 64 dims first, then aggregate + fused final linear)
    k_gemm_mfma<64><<<gemmGrid, 256, 0, stream>>>(bufH, W3hi, W3lo, bufT, N);
    k_agg64_final<<<aggGrid, 256, 0, stream>>>(bufT, out, row_start, cv, dinv, b3, Wf, bf, N);
}